// Round 2
// baseline (1502.233 us; speedup 1.0000x reference)
//
#include <hip/hip_runtime.h>
#include <stdint.h>

#define BS 32
#define SEQ 48
#define VOCAB 32529
#define HD 512
#define IMG_F 4096
#define EPS 1e-5f

typedef __attribute__((ext_vector_type(8))) short short8;
typedef __attribute__((ext_vector_type(4))) float f32x4;

#define MFMA(a, b, c) __builtin_amdgcn_mfma_f32_16x16x32_bf16(a, b, c, 0, 0, 0)

static __device__ __forceinline__ unsigned short f2bf(float v) {
  union { float f; unsigned u; } c; c.f = v;
  unsigned r = (c.u + 0x7FFFu + ((c.u >> 16) & 1u)) >> 16;
  return (unsigned short)r;
}
static __device__ __forceinline__ float bf2f(unsigned short h) {
  union { unsigned u; float f; } c; c.u = ((unsigned)h) << 16; return c.f;
}
static __device__ __forceinline__ float sigf(float x) {
  x = fminf(fmaxf(x, -30.f), 30.f);
  return 1.f / (1.f + __expf(-x));
}
static __device__ __forceinline__ float tanh_(float x) {
  float t = __expf(fminf(fmaxf(2.f * x, -30.f), 30.f));
  return (t - 1.f) / (t + 1.f);
}

// ---------- gather xe = emb[x] and split to bf16 hi/lo; rows m = t*32+b ----------
__global__ __launch_bounds__(256) void k_gather(const float* __restrict__ emb,
                                                const int* __restrict__ x,
                                                unsigned short* __restrict__ xh,
                                                unsigned short* __restrict__ xl) {
  int idx = blockIdx.x * 256 + threadIdx.x;  // one float4; total 1536*128
  int m = idx >> 7;
  int k4 = (idx & 127) << 2;
  int t = m >> 5, b = m & 31;
  int row = x[b * SEQ + t];
  float4 v = *(const float4*)(emb + (size_t)row * HD + k4);
  float vv[4] = {v.x, v.y, v.z, v.w};
  unsigned short h_[4], l_[4];
#pragma unroll
  for (int i = 0; i < 4; ++i) {
    h_[i] = f2bf(vv[i]);
    l_[i] = f2bf(vv[i] - bf2f(h_[i]));
  }
  ushort4 hq = {h_[0], h_[1], h_[2], h_[3]};
  ushort4 lq = {l_[0], l_[1], l_[2], l_[3]};
  *(ushort4*)(xh + (size_t)m * HD + k4) = hq;
  *(ushort4*)(xl + (size_t)m * HD + k4) = lq;
}

// ---------- pack a [512][2048] fp32 weight into split-bf16 MFMA B-fragment order ----------
// P[((n16*16 + kk)*64 + lane)*8 + i] = W[kk*32 + (lane>>4)*8 + i][n16*16 + (lane&15)]
__global__ __launch_bounds__(256) void k_pack(const float* __restrict__ W,
                                              unsigned short* __restrict__ Ph,
                                              unsigned short* __restrict__ Pl) {
  int f = blockIdx.x * 256 + threadIdx.x;  // 131072 frags
  int lane = f & 63;
  int kk = (f >> 6) & 15;
  int n16 = f >> 10;
  int c = n16 * 16 + (lane & 15);
  int k0 = kk * 32 + (lane >> 4) * 8;
  short8 oh, ol;
#pragma unroll
  for (int i = 0; i < 8; ++i) {
    float v = W[(size_t)(k0 + i) * 2048 + c];
    unsigned short hb = f2bf(v);
    oh[i] = (short)hb;
    ol[i] = (short)f2bf(v - bf2f(hb));
  }
  *(short8*)(Ph + (size_t)f * 8) = oh;
  *(short8*)(Pl + (size_t)f * 8) = ol;
}

// ---------- CNN layer: out = relu(BN(in @ W^T)); bias cancels in BN ----------
template <int INF, int OUTF>
__global__ __launch_bounds__(256) void k_cnn(const float* __restrict__ in,
                                             const float* __restrict__ W,
                                             const float* __restrict__ gamma,
                                             const float* __restrict__ beta,
                                             float* __restrict__ out) {
  int tid = threadIdx.x;
  int b = tid & 31;
  int o = blockIdx.x * 8 + (tid >> 5);
  const float4* ip = (const float4*)(in + (size_t)b * INF);
  const float4* wp = (const float4*)(W + (size_t)o * INF);
  float a0 = 0, a1 = 0, a2 = 0, a3 = 0;
#pragma unroll 4
  for (int k = 0; k < INF / 4; ++k) {
    float4 a = ip[k], w = wp[k];
    a0 = fmaf(a.x, w.x, a0);
    a1 = fmaf(a.y, w.y, a1);
    a2 = fmaf(a.z, w.z, a2);
    a3 = fmaf(a.w, w.w, a3);
  }
  float pre = (a0 + a1) + (a2 + a3);
  float s = pre, q = pre * pre;
#pragma unroll
  for (int mk = 16; mk >= 1; mk >>= 1) {
    s += __shfl_xor(s, mk);
    q += __shfl_xor(q, mk);
  }
  float mu = s * (1.f / 32.f);
  float var = q * (1.f / 32.f) - mu * mu;
  float y = gamma[o] * (pre - mu) * rsqrtf(var + EPS) + beta[o];
  out[(size_t)b * OUTF + o] = fmaxf(y, 0.f);
}

// ---------- xU GEMM: zx[m][0:2048] = xe[m] @ U + bg  (split-bf16, 3 terms) ----------
__global__ __launch_bounds__(256) void k_xu(const unsigned short* __restrict__ xh,
                                            const unsigned short* __restrict__ xl,
                                            const unsigned short* __restrict__ Uh,
                                            const unsigned short* __restrict__ Ul,
                                            const float* __restrict__ bg,
                                            float* __restrict__ zx) {
  int mb = blockIdx.x;  // 48
  int nb = blockIdx.y;  // 16
  int w = threadIdx.x >> 6, l = threadIdx.x & 63;
  int lr = l & 15, lg = l >> 4;
  f32x4 acc[2][2] = {};
#pragma unroll 2
  for (int kk = 0; kk < 16; ++kk) {
    short8 ah[2], al[2];
#pragma unroll
    for (int m = 0; m < 2; ++m) {
      size_t ao = (size_t)(mb * 32 + m * 16 + lr) * HD + kk * 32 + lg * 8;
      ah[m] = *(const short8*)(xh + ao);
      al[m] = *(const short8*)(xl + ao);
    }
#pragma unroll
    for (int n = 0; n < 2; ++n) {
      int n16 = nb * 8 + w * 2 + n;
      size_t bo = ((size_t)(n16 * 16 + kk) * 64 + l) * 8;
      short8 bh = *(const short8*)(Uh + bo);
      short8 bl = *(const short8*)(Ul + bo);
#pragma unroll
      for (int m = 0; m < 2; ++m) {
        acc[m][n] = MFMA(ah[m], bh, acc[m][n]);
        acc[m][n] = MFMA(al[m], bh, acc[m][n]);
        acc[m][n] = MFMA(ah[m], bl, acc[m][n]);
      }
    }
  }
#pragma unroll
  for (int m = 0; m < 2; ++m)
#pragma unroll
    for (int n = 0; n < 2; ++n) {
      int col = (nb * 8 + w * 2 + n) * 16 + lr;
#pragma unroll
      for (int r = 0; r < 4; ++r) {
        int row = mb * 32 + m * 16 + lg * 4 + r;
        zx[(size_t)row * 2048 + col] = acc[m][n][r] + bg[col];
      }
    }
}

// ---------- LSTM image step (h=0, c=0): z = feat (all gates) + bg ----------
__global__ __launch_bounds__(256) void k_step0(const float* __restrict__ feat,
                                               const float* __restrict__ bg,
                                               float* __restrict__ hbuf, float* __restrict__ cbuf,
                                               unsigned short* __restrict__ hh,
                                               unsigned short* __restrict__ hl) {
  int idx = blockIdx.x * 256 + threadIdx.x;  // 16384 = 32*512
  int j = idx & 511;
  float fv = feat[idx];
  float ig = sigf(fv + bg[j]);
  float gg = tanh_(fv + bg[1024 + j]);
  float og = sigf(fv + bg[1536 + j]);
  float c = ig * gg;  // f*c0 = 0
  float h = og * tanh_(c);
  cbuf[idx] = c;
  hbuf[idx] = h;
  unsigned short hb = f2bf(h);
  hh[idx] = hb;
  hl[idx] = f2bf(h - bf2f(hb));
}

// ---------- LSTM step t: z = zx[t] + h @ V (split-bf16); gates; update h,c ----------
__global__ __launch_bounds__(256) void k_step(int t,
    const unsigned short* __restrict__ hih, const unsigned short* __restrict__ hil,
    unsigned short* __restrict__ hoh, unsigned short* __restrict__ hol,
    const unsigned short* __restrict__ Vh, const unsigned short* __restrict__ Vl,
    const float* __restrict__ zx, float* __restrict__ cbuf, float* __restrict__ hbuf,
    unsigned short* __restrict__ hsb) {
  __shared__ float zsh[4][16][17];
  int nb = blockIdx.x & 31;  // j-tile
  int mh = blockIdx.x >> 5;  // batch half
  int w = threadIdx.x >> 6, l = threadIdx.x & 63;
  int lr = l & 15, lg = l >> 4;
  f32x4 acc = {};
  int n16 = w * 32 + nb;  // gate w, cols w*512 + nb*16 ..
#pragma unroll 4
  for (int kk = 0; kk < 16; ++kk) {
    size_t ao = (size_t)(mh * 16 + lr) * HD + kk * 32 + lg * 8;
    short8 ah = *(const short8*)(hih + ao);
    short8 al = *(const short8*)(hil + ao);
    size_t bo = ((size_t)(n16 * 16 + kk) * 64 + l) * 8;
    short8 bh = *(const short8*)(Vh + bo);
    short8 bl = *(const short8*)(Vl + bo);
    acc = MFMA(ah, bh, acc);
    acc = MFMA(al, bh, acc);
    acc = MFMA(ah, bl, acc);
  }
#pragma unroll
  for (int r = 0; r < 4; ++r) zsh[w][lg * 4 + r][lr] = acc[r];
  __syncthreads();
  int bl_ = threadIdx.x >> 4;  // 0..15
  int j = threadIdx.x & 15;
  int b = mh * 16 + bl_;
  int col = nb * 16 + j;
  const float* zr = zx + (size_t)(t * 32 + b) * 2048;
  float zi = zsh[0][bl_][j] + zr[col];
  float zf = zsh[1][bl_][j] + zr[512 + col];
  float zg = zsh[2][bl_][j] + zr[1024 + col];
  float zo = zsh[3][bl_][j] + zr[1536 + col];
  float ig = sigf(zi), fg = sigf(zf), gg = tanh_(zg), og = sigf(zo);
  int ci = b * HD + col;
  float c = fg * cbuf[ci] + ig * gg;
  float h = og * tanh_(c);
  cbuf[ci] = c;
  hbuf[ci] = h;
  unsigned short hb = f2bf(h);
  hoh[ci] = hb;
  hol[ci] = f2bf(h - bf2f(hb));
  hsb[((size_t)b * SEQ + t) * HD + col] = hb;
}

// ---------- output GEMM (+bias) -> exp -> rowsum / probs ----------
// MODE 0: rowsum only; MODE 1: write probs using rowsum; MODE 2: write exp + rowsum
template <int MODE>
__global__ __launch_bounds__(256) void k_out(const unsigned short* __restrict__ hsb,
                                             const float* __restrict__ Wout,
                                             const float* __restrict__ bout,
                                             float* __restrict__ rowsum,
                                             float* __restrict__ dst) {
  __shared__ __align__(16) unsigned short Bl[4][64][8];
  int nb = blockIdx.x, mb = blockIdx.y;
  int n0 = nb * 64;
  int tid = threadIdx.x;
  int w = tid >> 6, l = tid & 63, lr = l & 15, lg = l >> 4;
  int mrow0 = mb * 256 + w * 64;
  f32x4 acc[4][4] = {};
  int kl = tid >> 3;            // 0..31 (k within tile)
  int nl = (tid & 7) * 8;       // 0..56 (n within tile)
  int nsub = nl >> 4;
  int lbase = (nl & 15) | ((kl >> 3) << 4);
  int ifr = kl & 7;
  for (int kk = 0; kk < 16; ++kk) {
    float v[8];
    const float* src = Wout + (size_t)(kk * 32 + kl) * VOCAB + n0 + nl;
#pragma unroll
    for (int i = 0; i < 8; ++i) {
      int gv = n0 + nl + i;
      v[i] = (gv < VOCAB) ? src[i] : 0.f;
    }
    __syncthreads();
#pragma unroll
    for (int i = 0; i < 8; ++i) Bl[nsub][lbase + i][ifr] = f2bf(v[i]);
    __syncthreads();
    short8 a[4];
#pragma unroll
    for (int mt = 0; mt < 4; ++mt)
      a[mt] = *(const short8*)(hsb + (size_t)(mrow0 + mt * 16 + lr) * HD + kk * 32 + lg * 8);
#pragma unroll
    for (int nt = 0; nt < 4; ++nt) {
      short8 bf = *(const short8*)(&Bl[nt][l][0]);
#pragma unroll
      for (int mt = 0; mt < 4; ++mt) acc[mt][nt] = MFMA(a[mt], bf, acc[mt][nt]);
    }
  }
#pragma unroll
  for (int mt = 0; mt < 4; ++mt) {
#pragma unroll
    for (int r = 0; r < 4; ++r) {
      int row = mrow0 + mt * 16 + lg * 4 + r;
      float inv = 1.f;
      if (MODE == 1) inv = 1.f / rowsum[row];
      float s = 0.f;
#pragma unroll
      for (int nt = 0; nt < 4; ++nt) {
        int col = n0 + nt * 16 + lr;
        bool valid = col < VOCAB;
        float logit = acc[mt][nt][r] + (valid ? bout[col] : 0.f);
        float e = __expf(logit);
        if (MODE == 0) {
          s += valid ? e : 0.f;
        } else if (MODE == 2) {
          s += valid ? e : 0.f;
          if (valid) dst[(size_t)row * VOCAB + col] = e;
        } else {
          if (valid) dst[(size_t)row * VOCAB + col] = e * inv;
        }
      }
      if (MODE != 1) {
        s += __shfl_xor(s, 1);
        s += __shfl_xor(s, 2);
        s += __shfl_xor(s, 4);
        s += __shfl_xor(s, 8);
        if (lr == 0) atomicAdd(&rowsum[row], s);
      }
    }
  }
}

// ---------- divide pass (single-pass softmax path) ----------
__global__ __launch_bounds__(256) void k_div(const float* __restrict__ expb,
                                             const float* __restrict__ rowsum,
                                             float* __restrict__ out) {
  unsigned idx = blockIdx.x * 256u + threadIdx.x;  // 49,964,544 exact
  unsigned row = idx / (unsigned)VOCAB;
  out[idx] = expb[idx] / rowsum[row];
}

extern "C" void kernel_launch(void* const* d_in, const int* in_sizes, int n_in,
                              void* d_out, int out_size, void* d_ws, size_t ws_size,
                              hipStream_t stream) {
  const float* img  = (const float*)d_in[0];
  const int*   x    = (const int*)d_in[1];
  const float* w1   = (const float*)d_in[2];
  const float* g1   = (const float*)d_in[4];
  const float* be1  = (const float*)d_in[5];
  const float* w2   = (const float*)d_in[6];
  const float* g2   = (const float*)d_in[8];
  const float* be2  = (const float*)d_in[9];
  const float* w3   = (const float*)d_in[10];
  const float* g3   = (const float*)d_in[12];
  const float* be3  = (const float*)d_in[13];
  const float* U    = (const float*)d_in[14];
  const float* V    = (const float*)d_in[15];
  const float* bg   = (const float*)d_in[16];
  const float* emb  = (const float*)d_in[17];
  const float* Wout = (const float*)d_in[18];
  const float* bout = (const float*)d_in[19];

  char* ws = (char*)d_ws;
  size_t off = 0;
  auto alloc = [&](size_t bytes) -> void* {
    void* p = ws + off;
    off = (off + bytes + 255) & ~(size_t)255;
    return p;
  };
  float* zx = (float*)alloc((size_t)48 * 32 * 2048 * 4);
  unsigned short* xh = (unsigned short*)alloc((size_t)1536 * 512 * 2);
  unsigned short* xl = (unsigned short*)alloc((size_t)1536 * 512 * 2);
  unsigned short* Uh = (unsigned short*)alloc((size_t)512 * 2048 * 2);
  unsigned short* Ul = (unsigned short*)alloc((size_t)512 * 2048 * 2);
  unsigned short* Vh = (unsigned short*)alloc((size_t)512 * 2048 * 2);
  unsigned short* Vl = (unsigned short*)alloc((size_t)512 * 2048 * 2);
  unsigned short* hAh = (unsigned short*)alloc(32 * 512 * 2);
  unsigned short* hAl = (unsigned short*)alloc(32 * 512 * 2);
  unsigned short* hBh = (unsigned short*)alloc(32 * 512 * 2);
  unsigned short* hBl = (unsigned short*)alloc(32 * 512 * 2);
  float* hbuf = (float*)alloc(32 * 512 * 4);
  float* cbuf = (float*)alloc(32 * 512 * 4);
  unsigned short* hsb = (unsigned short*)alloc((size_t)1536 * 512 * 2);
  float* feat = (float*)alloc(32 * 512 * 4);
  float* h1 = (float*)alloc(32 * 2048 * 4);
  float* h2 = (float*)alloc(32 * 1024 * 4);
  float* rowsum = (float*)alloc(1536 * 4);
  size_t base = off;
  float* expb = (float*)(ws + base);
  const size_t EXPB = (size_t)49964544 * 4;
  bool onepass = (ws_size >= base + EXPB);

  float* out = (float*)d_out;

  k_gather<<<dim3(768), dim3(256), 0, stream>>>(emb, x, xh, xl);
  k_pack<<<dim3(512), dim3(256), 0, stream>>>(U, Uh, Ul);
  k_pack<<<dim3(512), dim3(256), 0, stream>>>(V, Vh, Vl);
  k_cnn<4096, 2048><<<dim3(256), dim3(256), 0, stream>>>(img, w1, g1, be1, h1);
  k_cnn<2048, 1024><<<dim3(128), dim3(256), 0, stream>>>(h1, w2, g2, be2, h2);
  k_cnn<1024, 512><<<dim3(64), dim3(256), 0, stream>>>(h2, w3, g3, be3, feat);
  k_xu<<<dim3(48, 16), dim3(256), 0, stream>>>(xh, xl, Uh, Ul, bg, zx);
  k_step0<<<dim3(64), dim3(256), 0, stream>>>(feat, bg, hbuf, cbuf, hAh, hAl);
  for (int t = 0; t < 48; ++t) {
    const unsigned short* ih = (t & 1) ? hBh : hAh;
    const unsigned short* il = (t & 1) ? hBl : hAl;
    unsigned short* oh = (t & 1) ? hAh : hBh;
    unsigned short* ol = (t & 1) ? hAl : hBl;
    k_step<<<dim3(64), dim3(256), 0, stream>>>(t, ih, il, oh, ol, Vh, Vl, zx, cbuf, hbuf, hsb);
  }
  hipMemsetAsync(rowsum, 0, 1536 * 4, stream);
  if (onepass) {
    k_out<2><<<dim3(509, 6), dim3(256), 0, stream>>>(hsb, Wout, bout, rowsum, expb);
    k_div<<<dim3(195174), dim3(256), 0, stream>>>(expb, rowsum, out);
  } else {
    k_out<0><<<dim3(509, 6), dim3(256), 0, stream>>>(hsb, Wout, bout, rowsum, out);
    k_out<1><<<dim3(509, 6), dim3(256), 0, stream>>>(hsb, Wout, bout, rowsum, out);
  }
  hipMemcpyAsync(out + 49964544, hbuf, 32 * 512 * 4, hipMemcpyDeviceToDevice, stream);
  hipMemcpyAsync(out + 49964544 + 16384, cbuf, 32 * 512 * 4, hipMemcpyDeviceToDevice, stream);
}